// Round 1
// baseline (4249.966 us; speedup 1.0000x reference)
//
#include <hip/hip_runtime.h>
#include <math.h>

#define N_NODES 50000
#define E_EDGES 800000
#define HC 128
#define ED 32

// ---- float <-> monotone-ordered uint for atomicMax on floats ----
__device__ __forceinline__ unsigned f2ord(float f){
    unsigned u = __float_as_uint(f);
    return (u & 0x80000000u) ? ~u : (u | 0x80000000u);
}
__device__ __forceinline__ float ord2f(unsigned u){
    return (u & 0x80000000u) ? __uint_as_float(u & 0x7fffffffu) : __uint_as_float(~u);
}
#define ORD_NEG_INF 0x007FFFFFu   // f2ord(-inf)

__global__ void init_seg_kernel(unsigned* __restrict__ amax, float* __restrict__ den, int n){
    int i = blockIdx.x * blockDim.x + threadIdx.x;
    if (i < n){ amax[i] = ORD_NEG_INF; den[i] = 0.f; }
}

__global__ void zero_kernel(float* __restrict__ p, int n){
    int i = blockIdx.x * blockDim.x + threadIdx.x;
    if (i < n) p[i] = 0.f;
}

// ---- Y[n_rows,128] = X[n_rows,K] @ W[K,128] + b ----
// block = 128 threads (1 col each), 16 rows per block, X tile staged in LDS.
template<int K>
__global__ void gemm_node(const float* __restrict__ X, const float* __restrict__ W,
                          const float* __restrict__ b, float* __restrict__ Y, int n_rows){
    __shared__ __align__(16) float xs[16 * K];
    const int t = threadIdx.x;            // 0..127 = output column
    const int row0 = blockIdx.x * 16;
    for (int idx = t; idx < 16 * K; idx += 128){
        int r = idx / K, c = idx % K;     // K is pow2 constant -> shifts
        int row = row0 + r;
        xs[idx] = (row < n_rows) ? X[row * K + c] : 0.f;
    }
    __syncthreads();
    float acc[16];
    const float bias = b[t];
    #pragma unroll
    for (int r = 0; r < 16; r++) acc[r] = bias;
    for (int k = 0; k < K; k += 4){
        float w0 = W[(k + 0) * HC + t];
        float w1 = W[(k + 1) * HC + t];
        float w2 = W[(k + 2) * HC + t];
        float w3 = W[(k + 3) * HC + t];
        #pragma unroll
        for (int r = 0; r < 16; r++){
            float4 xv = *(const float4*)&xs[r * K + k];
            acc[r] += xv.x * w0 + xv.y * w1 + xv.z * w2 + xv.w * w3;
        }
    }
    #pragma unroll
    for (int r = 0; r < 16; r++){
        int row = row0 + r;
        if (row < n_rows) Y[row * HC + t] = acc[r];
    }
}

// ---- per-edge alpha = <q[dst], k[src] + attr@We> / sqrt(32); atomicMax amax ----
// block 256 = 2 edges x 128 threads; thread = (h = lane>>5, c = lane&31)
__global__ void edge_alpha_kernel(const float* __restrict__ q, const float* __restrict__ k,
                                  const float* __restrict__ attr, const float* __restrict__ We,
                                  const int* __restrict__ src, const int* __restrict__ dst,
                                  float* __restrict__ a_out, unsigned* __restrict__ amax,
                                  int n_edges){
    __shared__ float We_s[ED * HC];
    const int t = threadIdx.x;
    for (int i = t; i < ED * HC; i += 256) We_s[i] = We[i];
    __syncthreads();
    const int lane = t & 127, le = t >> 7;
    const int h = lane >> 5, c = lane & 31;
    const int nep = (n_edges + 1) >> 1;
    for (int pair = blockIdx.x; pair < nep; pair += gridDim.x){
        int e = pair * 2 + le;
        if (e >= n_edges) continue;
        int s = src[e], d = dst[e];
        const float* arow = attr + (size_t)e * ED;
        float ev = 0.f;
        #pragma unroll
        for (int dd = 0; dd < ED; dd++) ev += arow[dd] * We_s[dd * HC + lane];
        float kj = k[(size_t)s * HC + lane] + ev;
        float prod = q[(size_t)d * HC + lane] * kj;
        #pragma unroll
        for (int off = 16; off; off >>= 1) prod += __shfl_down(prod, off, 32);
        if (c == 0){
            float alpha = prod * 0.17677669529663687f;  // 1/sqrt(32)
            a_out[e * 4 + h] = alpha;
            atomicMax(&amax[d * 4 + h], f2ord(alpha));
        }
    }
}

// ---- ex = exp(alpha - amax[dst]); accumulate den and ex*(v[src]+e) ----
__global__ void edge_agg_kernel(const float* __restrict__ v,
                                const float* __restrict__ attr, const float* __restrict__ We,
                                const int* __restrict__ src, const int* __restrict__ dst,
                                float* __restrict__ a_out, const unsigned* __restrict__ amax,
                                float* __restrict__ den, float* __restrict__ vacc,
                                int n_edges){
    __shared__ float We_s[ED * HC];
    const int t = threadIdx.x;
    for (int i = t; i < ED * HC; i += 256) We_s[i] = We[i];
    __syncthreads();
    const int lane = t & 127, le = t >> 7;
    const int h = lane >> 5, c = lane & 31;
    const int nep = (n_edges + 1) >> 1;
    for (int pair = blockIdx.x; pair < nep; pair += gridDim.x){
        int e = pair * 2 + le;
        if (e >= n_edges) continue;
        int s = src[e], d = dst[e];
        float alpha = a_out[e * 4 + h];
        float am = ord2f(amax[d * 4 + h]);
        float ex = expf(alpha - am);
        const float* arow = attr + (size_t)e * ED;
        float ev = 0.f;
        #pragma unroll
        for (int dd = 0; dd < ED; dd++) ev += arow[dd] * We_s[dd * HC + lane];
        float vj = v[(size_t)s * HC + lane] + ev;
        atomicAdd(&vacc[(size_t)d * HC + lane], ex * vj);
        if (c == 0){
            a_out[e * 4 + h] = ex;
            atomicAdd(&den[d * 4 + h], ex);
        }
    }
}

// ---- a = ex / (den[dst] + 1e-16) ----
__global__ void norm_a_kernel(float* __restrict__ a_out, const float* __restrict__ den,
                              const int* __restrict__ dst, int n){
    int i = blockIdx.x * blockDim.x + threadIdx.x;   // over E*4
    if (i < n){
        int e = i >> 2, h = i & 3;
        a_out[i] = a_out[i] / (den[dst[e] * 4 + h] + 1e-16f);
    }
}

// ---- per-node epilogue: out = vacc/(den+eps) + skip; optional LN+ReLU ----
// one wave (64 lanes) per node, 2 channels per lane
__global__ void node_ln_kernel(const float* __restrict__ vacc, const float* __restrict__ den,
                               const float* __restrict__ skip, const float* __restrict__ g,
                               const float* __restrict__ be, float* __restrict__ out,
                               int n_rows, int apply_ln){
    const int wave = threadIdx.x >> 6;
    const int lane = threadIdx.x & 63;
    const int n = blockIdx.x * (blockDim.x >> 6) + wave;
    if (n >= n_rows) return;
    float vals[2];
    #pragma unroll
    for (int j = 0; j < 2; j++){
        int cidx = lane + 64 * j;
        int h = cidx >> 5;
        float dd = den[n * 4 + h] + 1e-16f;
        vals[j] = vacc[(size_t)n * HC + cidx] / dd + skip[(size_t)n * HC + cidx];
    }
    if (apply_ln){
        float s = vals[0] + vals[1];
        float ss = vals[0] * vals[0] + vals[1] * vals[1];
        #pragma unroll
        for (int off = 32; off; off >>= 1){ s += __shfl_down(s, off); ss += __shfl_down(ss, off); }
        s = __shfl(s, 0); ss = __shfl(ss, 0);
        float m = s * (1.f / 128.f);
        float var = ss * (1.f / 128.f) - m * m;
        float inv = rsqrtf(var + 1e-5f);
        #pragma unroll
        for (int j = 0; j < 2; j++){
            int cidx = lane + 64 * j;
            float y = (vals[j] - m) * inv * g[cidx] + be[cidx];
            out[(size_t)n * HC + cidx] = fmaxf(y, 0.f);
        }
    } else {
        #pragma unroll
        for (int j = 0; j < 2; j++)
            out[(size_t)n * HC + lane + 64 * j] = vals[j];
    }
}

extern "C" void kernel_launch(void* const* d_in, const int* in_sizes, int n_in,
                              void* d_out, int out_size, void* d_ws, size_t ws_size,
                              hipStream_t stream) {
    const float* x    = (const float*)d_in[0];
    const int*   ei   = (const int*)  d_in[1];
    const float* attr = (const float*)d_in[2];
    const float* gln[2]  = { (const float*)d_in[30], (const float*)d_in[32] };
    const float* beln[2] = { (const float*)d_in[31], (const float*)d_in[33] };

    float* out   = (float*)d_out;
    float* h_out = out;                               // [N,128]
    float* a_out[3] = { out + (size_t)N_NODES * HC,
                        out + (size_t)N_NODES * HC + (size_t)E_EDGES * 4,
                        out + (size_t)N_NODES * HC + (size_t)2 * E_EDGES * 4 };

    float* ws   = (float*)d_ws;
    const size_t NB = (size_t)N_NODES * HC;
    float* H    = ws;            // layer activations [N,128]
    float* qbuf = ws + NB;       // q, then reused as vacc
    float* kbuf = ws + 2 * NB;
    float* vbuf = ws + 3 * NB;
    float* sbuf = ws + 4 * NB;   // skip = x@Ws + bs
    float* den  = ws + 5 * NB;               // [N,4]
    unsigned* amax = (unsigned*)(den + (size_t)N_NODES * 4);  // [N,4]

    const int* srcp = ei;
    const int* dstp = ei + E_EDGES;

    for (int l = 0; l < 3; l++){
        const float* Wq = (const float*)d_in[3 + 9 * l + 0];
        const float* bq = (const float*)d_in[3 + 9 * l + 1];
        const float* Wk = (const float*)d_in[3 + 9 * l + 2];
        const float* bk = (const float*)d_in[3 + 9 * l + 3];
        const float* Wv = (const float*)d_in[3 + 9 * l + 4];
        const float* bv = (const float*)d_in[3 + 9 * l + 5];
        const float* We = (const float*)d_in[3 + 9 * l + 6];
        const float* Ws = (const float*)d_in[3 + 9 * l + 7];
        const float* bs = (const float*)d_in[3 + 9 * l + 8];
        const float* Xin = (l == 0) ? x : H;

        const int gemm_grid = (N_NODES + 15) / 16;
        if (l == 0){
            gemm_node<256><<<gemm_grid, 128, 0, stream>>>(Xin, Wq, bq, qbuf, N_NODES);
            gemm_node<256><<<gemm_grid, 128, 0, stream>>>(Xin, Wk, bk, kbuf, N_NODES);
            gemm_node<256><<<gemm_grid, 128, 0, stream>>>(Xin, Wv, bv, vbuf, N_NODES);
            gemm_node<256><<<gemm_grid, 128, 0, stream>>>(Xin, Ws, bs, sbuf, N_NODES);
        } else {
            gemm_node<128><<<gemm_grid, 128, 0, stream>>>(Xin, Wq, bq, qbuf, N_NODES);
            gemm_node<128><<<gemm_grid, 128, 0, stream>>>(Xin, Wk, bk, kbuf, N_NODES);
            gemm_node<128><<<gemm_grid, 128, 0, stream>>>(Xin, Wv, bv, vbuf, N_NODES);
            gemm_node<128><<<gemm_grid, 128, 0, stream>>>(Xin, Ws, bs, sbuf, N_NODES);
        }

        init_seg_kernel<<<(N_NODES * 4 + 255) / 256, 256, 0, stream>>>(amax, den, N_NODES * 4);
        edge_alpha_kernel<<<2048, 256, 0, stream>>>(qbuf, kbuf, attr, We, srcp, dstp,
                                                    a_out[l], amax, E_EDGES);
        // q is dead now; reuse it as the vacc accumulator
        zero_kernel<<<(N_NODES * HC + 255) / 256, 256, 0, stream>>>(qbuf, N_NODES * HC);
        edge_agg_kernel<<<2048, 256, 0, stream>>>(vbuf, attr, We, srcp, dstp,
                                                  a_out[l], amax, den, qbuf, E_EDGES);
        norm_a_kernel<<<(E_EDGES * 4 + 255) / 256, 256, 0, stream>>>(a_out[l], den, dstp, E_EDGES * 4);

        if (l < 2){
            node_ln_kernel<<<(N_NODES + 3) / 4, 256, 0, stream>>>(qbuf, den, sbuf,
                                                                  gln[l], beln[l], H, N_NODES, 1);
        } else {
            node_ln_kernel<<<(N_NODES + 3) / 4, 256, 0, stream>>>(qbuf, den, sbuf,
                                                                  nullptr, nullptr, h_out, N_NODES, 0);
        }
    }
}

// Round 2
// 2983.722 us; speedup vs baseline: 1.4244x; 1.4244x over previous
//
#include <hip/hip_runtime.h>
#include <math.h>

#define N_NODES 50000
#define E_EDGES 800000
#define HC 128
#define ED 32

// ============================ CSR build ============================

__global__ void zero_int_kernel(int* __restrict__ p, int n){
    int i = blockIdx.x * blockDim.x + threadIdx.x;
    if (i < n) p[i] = 0;
}

__global__ void hist_kernel(const int* __restrict__ dst, int* __restrict__ cnt, int n_edges){
    int e = blockIdx.x * blockDim.x + threadIdx.x;
    if (e < n_edges) atomicAdd(&cnt[dst[e]], 1);
}

// single block of 1024 threads: exclusive scan of cnt[N] -> rowptr[N+1] and cursor[N]
__global__ void scan_kernel(const int* __restrict__ cnt, int* __restrict__ rowptr,
                            int* __restrict__ cursor){
    __shared__ int part[1024];
    const int t = threadIdx.x;
    const int CH = (N_NODES + 1023) / 1024;   // 49
    const int base = t * CH;
    int s = 0;
    for (int i = 0; i < CH; i++){
        int idx = base + i;
        if (idx < N_NODES) s += cnt[idx];
    }
    part[t] = s;
    __syncthreads();
    for (int off = 1; off < 1024; off <<= 1){
        int v = (t >= off) ? part[t - off] : 0;
        __syncthreads();
        part[t] += v;
        __syncthreads();
    }
    int off = (t == 0) ? 0 : part[t - 1];
    for (int i = 0; i < CH; i++){
        int idx = base + i;
        if (idx < N_NODES){
            int c = cnt[idx];
            rowptr[idx] = off;
            cursor[idx] = off;
            off += c;
        }
    }
    if (t == 1023) rowptr[N_NODES] = part[1023];
}

__global__ void scatter_kernel(const int* __restrict__ src, const int* __restrict__ dst,
                               int* __restrict__ cursor, int* __restrict__ eids,
                               int* __restrict__ srcs, int n_edges){
    int e = blockIdx.x * blockDim.x + threadIdx.x;
    if (e < n_edges){
        int d = dst[e];
        int pos = atomicAdd(&cursor[d], 1);
        eids[pos] = e;
        srcs[pos] = src[e];
    }
}

// ============================ node GEMM ============================
// Y[n_rows,128] = X[n_rows,K] @ W[K,128] + b
template<int K>
__global__ void gemm_node(const float* __restrict__ X, const float* __restrict__ W,
                          const float* __restrict__ b, float* __restrict__ Y, int n_rows){
    __shared__ __align__(16) float xs[16 * K];
    const int t = threadIdx.x;            // 0..127 = output column
    const int row0 = blockIdx.x * 16;
    for (int idx = t; idx < 16 * K; idx += 128){
        int r = idx / K, c = idx % K;
        int row = row0 + r;
        xs[idx] = (row < n_rows) ? X[row * K + c] : 0.f;
    }
    __syncthreads();
    float acc[16];
    const float bias = b[t];
    #pragma unroll
    for (int r = 0; r < 16; r++) acc[r] = bias;
    for (int k = 0; k < K; k += 4){
        float w0 = W[(k + 0) * HC + t];
        float w1 = W[(k + 1) * HC + t];
        float w2 = W[(k + 2) * HC + t];
        float w3 = W[(k + 3) * HC + t];
        #pragma unroll
        for (int r = 0; r < 16; r++){
            float4 xv = *(const float4*)&xs[r * K + k];
            acc[r] += xv.x * w0 + xv.y * w1 + xv.z * w2 + xv.w * w3;
        }
    }
    #pragma unroll
    for (int r = 0; r < 16; r++){
        int row = row0 + r;
        if (row < n_rows) Y[row * HC + t] = acc[r];
    }
}

// ===================== fused per-node attention =====================
// one wave (64 lanes) per destination node; online softmax in registers;
// We columns cached in VGPRs; epilogue (skip + LN + ReLU) fused.
__global__ __launch_bounds__(256) void fused_attn_kernel(
    const float* __restrict__ q, const float* __restrict__ k, const float* __restrict__ v,
    const float* __restrict__ skip, const float* __restrict__ attr, const float* __restrict__ We,
    const int* __restrict__ rowptr, const int* __restrict__ eids, const int* __restrict__ srcs,
    float* __restrict__ a_raw, float* __restrict__ mbuf, float* __restrict__ dbuf,
    const float* __restrict__ g, const float* __restrict__ be,
    float* __restrict__ out, int apply_ln)
{
    const int lane = threadIdx.x & 63;
    const int wv = threadIdx.x >> 6;
    const int n = blockIdx.x * 4 + wv;
    if (n >= N_NODES) return;
    const int c0 = lane, c1 = lane + 64;

    // cache this lane's two We columns in registers (one-time, reused for all edges)
    float w0[32], w1[32];
    #pragma unroll
    for (int d = 0; d < 32; d++){ w0[d] = We[d * HC + c0]; w1[d] = We[d * HC + c1]; }

    const float q0 = q[(size_t)n * HC + c0];
    const float q1 = q[(size_t)n * HC + c1];
    const int beg = rowptr[n], end = rowptr[n + 1];

    float mA = -1e30f, sA = 0.f, acc0 = 0.f;   // heads (lane<32 ? 0 : 1)
    float mB = -1e30f, sB = 0.f, acc1 = 0.f;   // heads (lane<32 ? 2 : 3)

    for (int i = beg; i < end; i++){
        const int e = eids[i], s = srcs[i];
        float av = attr[(size_t)e * ED + (lane & 31)];
        float k0 = k[(size_t)s * HC + c0], k1 = k[(size_t)s * HC + c1];
        float v0 = v[(size_t)s * HC + c0], v1 = v[(size_t)s * HC + c1];

        float ep0 = 0.f, ep1 = 0.f;
        #pragma unroll
        for (int d = 0; d < 32; d++){
            float ad = __shfl(av, d, 32);
            ep0 = fmaf(ad, w0[d], ep0);
            ep1 = fmaf(ad, w1[d], ep1);
        }

        float p0 = q0 * (k0 + ep0);
        float p1 = q1 * (k1 + ep1);
        #pragma unroll
        for (int off = 16; off; off >>= 1){
            p0 += __shfl_xor(p0, off);
            p1 += __shfl_xor(p1, off);
        }
        const float aA = p0 * 0.17677669529663687f;  // 1/sqrt(32)
        const float aB = p1 * 0.17677669529663687f;

        if (lane == 0)       { a_raw[(size_t)e * 4 + 0] = aA; a_raw[(size_t)e * 4 + 2] = aB; }
        else if (lane == 32) { a_raw[(size_t)e * 4 + 1] = aA; a_raw[(size_t)e * 4 + 3] = aB; }

        const float vj0 = v0 + ep0, vj1 = v1 + ep1;

        float mAn = fmaxf(mA, aA);
        float scA = __expf(mA - mAn), wA = __expf(aA - mAn);
        sA = sA * scA + wA; acc0 = acc0 * scA + wA * vj0; mA = mAn;

        float mBn = fmaxf(mB, aB);
        float scB = __expf(mB - mBn), wB = __expf(aB - mBn);
        sB = sB * scB + wB; acc1 = acc1 * scB + wB * vj1; mB = mBn;
    }

    if (lane == 0)       { mbuf[n * 4 + 0] = mA; mbuf[n * 4 + 2] = mB;
                           dbuf[n * 4 + 0] = sA; dbuf[n * 4 + 2] = sB; }
    else if (lane == 32) { mbuf[n * 4 + 1] = mA; mbuf[n * 4 + 3] = mB;
                           dbuf[n * 4 + 1] = sA; dbuf[n * 4 + 3] = sB; }

    float o0 = acc0 / (sA + 1e-16f) + skip[(size_t)n * HC + c0];
    float o1 = acc1 / (sB + 1e-16f) + skip[(size_t)n * HC + c1];

    if (apply_ln){
        float s1 = o0 + o1, s2 = o0 * o0 + o1 * o1;
        #pragma unroll
        for (int off = 32; off; off >>= 1){
            s1 += __shfl_xor(s1, off);
            s2 += __shfl_xor(s2, off);
        }
        float m = s1 * (1.f / 128.f);
        float var = s2 * (1.f / 128.f) - m * m;
        float inv = rsqrtf(var + 1e-5f);
        o0 = fmaxf((o0 - m) * inv * g[c0] + be[c0], 0.f);
        o1 = fmaxf((o1 - m) * inv * g[c1] + be[c1], 0.f);
    }
    out[(size_t)n * HC + c0] = o0;
    out[(size_t)n * HC + c1] = o1;
}

// ---- a = exp(raw - m[dst]) / (den[dst] + 1e-16) ----
__global__ void norm_a_kernel(float* __restrict__ a, const float* __restrict__ mbuf,
                              const float* __restrict__ dbuf, const int* __restrict__ dst,
                              int n){   // n = E*4
    int i = blockIdx.x * blockDim.x + threadIdx.x;
    if (i < n){
        int e = i >> 2, h = i & 3;
        int d = dst[e];
        a[i] = __expf(a[i] - mbuf[d * 4 + h]) / (dbuf[d * 4 + h] + 1e-16f);
    }
}

// ============================ launch ============================

extern "C" void kernel_launch(void* const* d_in, const int* in_sizes, int n_in,
                              void* d_out, int out_size, void* d_ws, size_t ws_size,
                              hipStream_t stream) {
    const float* x    = (const float*)d_in[0];
    const int*   ei   = (const int*)  d_in[1];
    const float* attr = (const float*)d_in[2];
    const float* gln[2]  = { (const float*)d_in[30], (const float*)d_in[32] };
    const float* beln[2] = { (const float*)d_in[31], (const float*)d_in[33] };

    float* out   = (float*)d_out;
    float* h_out = out;                               // [N,128]
    float* a_out[3] = { out + (size_t)N_NODES * HC,
                        out + (size_t)N_NODES * HC + (size_t)E_EDGES * 4,
                        out + (size_t)N_NODES * HC + (size_t)2 * E_EDGES * 4 };

    float* ws = (float*)d_ws;
    const size_t NB = (size_t)N_NODES * HC;
    float* H    = ws;            // layer activations [N,128]
    float* qbuf = ws + NB;
    float* kbuf = ws + 2 * NB;
    float* vbuf = ws + 3 * NB;
    float* sbuf = ws + 4 * NB;   // skip = x@Ws + bs
    float* mbuf = ws + 5 * NB;                    // [N,4]
    float* dbuf = mbuf + (size_t)N_NODES * 4;     // [N,4]
    int* ibase  = (int*)(dbuf + (size_t)N_NODES * 4);
    int* cnt    = ibase;                  // [N]
    int* rowptr = cnt + N_NODES;          // [N+1]
    int* cursor = rowptr + N_NODES + 1;   // [N]
    int* eids   = cursor + N_NODES;       // [E]
    int* srcs   = eids + E_EDGES;         // [E]

    const int* srcp = ei;
    const int* dstp = ei + E_EDGES;

    // ---- CSR build (once per launch, reused for all 3 layers) ----
    zero_int_kernel<<<(N_NODES + 255) / 256, 256, 0, stream>>>(cnt, N_NODES);
    hist_kernel<<<(E_EDGES + 255) / 256, 256, 0, stream>>>(dstp, cnt, E_EDGES);
    scan_kernel<<<1, 1024, 0, stream>>>(cnt, rowptr, cursor);
    scatter_kernel<<<(E_EDGES + 255) / 256, 256, 0, stream>>>(srcp, dstp, cursor, eids, srcs, E_EDGES);

    for (int l = 0; l < 3; l++){
        const float* Wq = (const float*)d_in[3 + 9 * l + 0];
        const float* bq = (const float*)d_in[3 + 9 * l + 1];
        const float* Wk = (const float*)d_in[3 + 9 * l + 2];
        const float* bk = (const float*)d_in[3 + 9 * l + 3];
        const float* Wv = (const float*)d_in[3 + 9 * l + 4];
        const float* bv = (const float*)d_in[3 + 9 * l + 5];
        const float* We = (const float*)d_in[3 + 9 * l + 6];
        const float* Ws = (const float*)d_in[3 + 9 * l + 7];
        const float* bs = (const float*)d_in[3 + 9 * l + 8];
        const float* Xin = (l == 0) ? x : H;

        const int gemm_grid = (N_NODES + 15) / 16;
        if (l == 0){
            gemm_node<256><<<gemm_grid, 128, 0, stream>>>(Xin, Wq, bq, qbuf, N_NODES);
            gemm_node<256><<<gemm_grid, 128, 0, stream>>>(Xin, Wk, bk, kbuf, N_NODES);
            gemm_node<256><<<gemm_grid, 128, 0, stream>>>(Xin, Wv, bv, vbuf, N_NODES);
            gemm_node<256><<<gemm_grid, 128, 0, stream>>>(Xin, Ws, bs, sbuf, N_NODES);
        } else {
            gemm_node<128><<<gemm_grid, 128, 0, stream>>>(Xin, Wq, bq, qbuf, N_NODES);
            gemm_node<128><<<gemm_grid, 128, 0, stream>>>(Xin, Wk, bk, kbuf, N_NODES);
            gemm_node<128><<<gemm_grid, 128, 0, stream>>>(Xin, Wv, bv, vbuf, N_NODES);
            gemm_node<128><<<gemm_grid, 128, 0, stream>>>(Xin, Ws, bs, sbuf, N_NODES);
        }

        float* dest = (l < 2) ? H : h_out;
        const float* gg = (l < 2) ? gln[l] : nullptr;
        const float* bb = (l < 2) ? beln[l] : nullptr;
        fused_attn_kernel<<<(N_NODES + 3) / 4, 256, 0, stream>>>(
            qbuf, kbuf, vbuf, sbuf, attr, We, rowptr, eids, srcs,
            a_out[l], mbuf, dbuf, gg, bb, dest, (l < 2) ? 1 : 0);

        norm_a_kernel<<<(E_EDGES * 4 + 255) / 256, 256, 0, stream>>>(
            a_out[l], mbuf, dbuf, dstp, E_EDGES * 4);
    }
}

// Round 3
// 2493.514 us; speedup vs baseline: 1.7044x; 1.1966x over previous
//
#include <hip/hip_runtime.h>
#include <math.h>

#define N_NODES 50000
#define E_EDGES 800000
#define HC 128
#define ED 32

// ============================ CSR build ============================

__global__ void zero_int_kernel(int* __restrict__ p, int n){
    int i = blockIdx.x * blockDim.x + threadIdx.x;
    if (i < n) p[i] = 0;
}

__global__ void hist_kernel(const int* __restrict__ dst, int* __restrict__ cnt, int n_edges){
    int e = blockIdx.x * blockDim.x + threadIdx.x;
    if (e < n_edges) atomicAdd(&cnt[dst[e]], 1);
}

// single block of 1024 threads: exclusive scan of cnt[N] -> rowptr[N+1] and cursor[N]
__global__ void scan_kernel(const int* __restrict__ cnt, int* __restrict__ rowptr,
                            int* __restrict__ cursor){
    __shared__ int part[1024];
    const int t = threadIdx.x;
    const int CH = (N_NODES + 1023) / 1024;   // 49
    const int base = t * CH;
    int s = 0;
    for (int i = 0; i < CH; i++){
        int idx = base + i;
        if (idx < N_NODES) s += cnt[idx];
    }
    part[t] = s;
    __syncthreads();
    for (int off = 1; off < 1024; off <<= 1){
        int v = (t >= off) ? part[t - off] : 0;
        __syncthreads();
        part[t] += v;
        __syncthreads();
    }
    int off = (t == 0) ? 0 : part[t - 1];
    for (int i = 0; i < CH; i++){
        int idx = base + i;
        if (idx < N_NODES){
            int c = cnt[idx];
            rowptr[idx] = off;
            cursor[idx] = off;
            off += c;
        }
    }
    if (t == 1023) rowptr[N_NODES] = part[1023];
}

__global__ void scatter_kernel(const int* __restrict__ src, const int* __restrict__ dst,
                               int* __restrict__ cursor, int2* __restrict__ es, int n_edges){
    int e = blockIdx.x * blockDim.x + threadIdx.x;
    if (e < n_edges){
        int d = dst[e];
        int pos = atomicAdd(&cursor[d], 1);
        es[pos] = make_int2(e, src[e]);
    }
}

// ============================ node GEMM ============================
// Y[n_rows,128] = X[n_rows,K] @ W[K,128] + b
template<int K>
__global__ void gemm_node(const float* __restrict__ X, const float* __restrict__ W,
                          const float* __restrict__ b, float* __restrict__ Y, int n_rows){
    __shared__ __align__(16) float xs[16 * K];
    const int t = threadIdx.x;            // 0..127 = output column
    const int row0 = blockIdx.x * 16;
    for (int idx = t; idx < 16 * K; idx += 128){
        int r = idx / K, c = idx % K;
        int row = row0 + r;
        xs[idx] = (row < n_rows) ? X[row * K + c] : 0.f;
    }
    __syncthreads();
    float acc[16];
    const float bias = b[t];
    #pragma unroll
    for (int r = 0; r < 16; r++) acc[r] = bias;
    for (int k = 0; k < K; k += 4){
        float w0 = W[(k + 0) * HC + t];
        float w1 = W[(k + 1) * HC + t];
        float w2 = W[(k + 2) * HC + t];
        float w3 = W[(k + 3) * HC + t];
        #pragma unroll
        for (int r = 0; r < 16; r++){
            float4 xv = *(const float4*)&xs[r * K + k];
            acc[r] += xv.x * w0 + xv.y * w1 + xv.z * w2 + xv.w * w3;
        }
    }
    #pragma unroll
    for (int r = 0; r < 16; r++){
        int row = row0 + r;
        if (row < n_rows) Y[row * HC + t] = acc[r];
    }
}

// ===================== fused per-node attention =====================
// One wave per destination node. Key algebra:
//   alpha = (q.k[src] + attr . QW[dst]) / sqrt(32),  QW[n,h,d] = sum_c q[n,h,c] We[d,h*32+c]
//   out_e-part = We^T S,  S[h,d] = sum_e w_e[h] attr[e,d]   (applied once per node)
// so the per-edge work has NO 32-iter mat-vec.
__global__ __launch_bounds__(256) void fused_attn_kernel(
    const float* __restrict__ q, const float* __restrict__ k, const float* __restrict__ v,
    const float* __restrict__ skip, const float* __restrict__ attr, const float* __restrict__ We,
    const int* __restrict__ rowptr, const int2* __restrict__ es,
    float* __restrict__ a_raw, float* __restrict__ mbuf, float* __restrict__ dbuf,
    const float* __restrict__ g, const float* __restrict__ be,
    float* __restrict__ out, int apply_ln)
{
    __shared__ float WeR[ED * HC];   // [d*128 + c]  (epilogue reads: 2-way alias, free)
    __shared__ float WeT[HC * ED];   // [c*32 + d]   (QW loop reads: 2-way alias, free)
    const int t = threadIdx.x;
    for (int idx = t; idx < ED * HC; idx += 256){
        float w = We[idx];
        int d = idx >> 7, c = idx & 127;
        WeR[idx] = w;
        WeT[c * ED + d] = w;
    }
    __syncthreads();

    const int lane = t & 63, wv = t >> 6;
    const int n = blockIdx.x * 4 + wv;
    if (n >= N_NODES) return;
    const int c0 = lane, c1 = lane + 64;
    const int hsel = lane & 32;      // head-group selector within the wave
    const int d0 = lane & 31;

    const float q0 = q[(size_t)n * HC + c0];
    const float q1 = q[(size_t)n * HC + c1];

    // QW for this lane's two (h,d) slots — once per node
    float QW0 = 0.f, QW1 = 0.f;
    #pragma unroll
    for (int c = 0; c < 32; c++){
        float sq0 = __shfl(q0, hsel + c);
        float sq1 = __shfl(q1, hsel + c);
        QW0 = fmaf(sq0, WeT[(hsel + c) * ED + d0], QW0);
        QW1 = fmaf(sq1, WeT[(64 + hsel + c) * ED + d0], QW1);
    }

    const int beg = rowptr[n], end = rowptr[n + 1];
    float mA = -1e30f, sA = 0.f, acc0 = 0.f, S0 = 0.f;  // heads (lane<32 ? 0 : 1)
    float mB = -1e30f, sB = 0.f, acc1 = 0.f, S1 = 0.f;  // heads (lane<32 ? 2 : 3)

    auto process = [&](int e, float av, float k0, float k1, float v0, float v1){
        float p0 = fmaf(av, QW0, q0 * k0);
        float p1 = fmaf(av, QW1, q1 * k1);
        #pragma unroll
        for (int off = 16; off; off >>= 1){
            p0 += __shfl_xor(p0, off);
            p1 += __shfl_xor(p1, off);
        }
        const float aA = p0 * 0.17677669529663687f;  // 1/sqrt(32)
        const float aB = p1 * 0.17677669529663687f;
        if (lane == 0)       { a_raw[(size_t)e * 4 + 0] = aA; a_raw[(size_t)e * 4 + 2] = aB; }
        else if (lane == 32) { a_raw[(size_t)e * 4 + 1] = aA; a_raw[(size_t)e * 4 + 3] = aB; }
        float mAn = fmaxf(mA, aA);
        float scA = __expf(mA - mAn), wA = __expf(aA - mAn);
        sA = fmaf(sA, scA, wA);
        acc0 = fmaf(acc0, scA, wA * v0);
        S0   = fmaf(S0,   scA, wA * av);
        mA = mAn;
        float mBn = fmaxf(mB, aB);
        float scB = __expf(mB - mBn), wB = __expf(aB - mBn);
        sB = fmaf(sB, scB, wB);
        acc1 = fmaf(acc1, scB, wB * v1);
        S1   = fmaf(S1,   scB, wB * av);
        mB = mBn;
    };

    int i = beg;
    for (; i + 1 < end; i += 2){
        int2 e0 = es[i], e1 = es[i + 1];
        float av0 = attr[(size_t)e0.x * ED + d0];
        float av1 = attr[(size_t)e1.x * ED + d0];
        const float* kp0 = k + (size_t)e0.y * HC;
        const float* vp0 = v + (size_t)e0.y * HC;
        const float* kp1 = k + (size_t)e1.y * HC;
        const float* vp1 = v + (size_t)e1.y * HC;
        float k00 = kp0[c0], k01 = kp0[c1], v00 = vp0[c0], v01 = vp0[c1];
        float k10 = kp1[c0], k11 = kp1[c1], v10 = vp1[c0], v11 = vp1[c1];
        process(e0.x, av0, k00, k01, v00, v01);
        process(e1.x, av1, k10, k11, v10, v11);
    }
    if (i < end){
        int2 e0 = es[i];
        float av0 = attr[(size_t)e0.x * ED + d0];
        const float* kp0 = k + (size_t)e0.y * HC;
        const float* vp0 = v + (size_t)e0.y * HC;
        process(e0.x, av0, kp0[c0], kp0[c1], vp0[c0], vp0[c1]);
    }

    if (lane == 0)       { mbuf[n * 4 + 0] = mA; mbuf[n * 4 + 2] = mB;
                           dbuf[n * 4 + 0] = sA; dbuf[n * 4 + 2] = sB; }
    else if (lane == 32) { mbuf[n * 4 + 1] = mA; mbuf[n * 4 + 3] = mB;
                           dbuf[n * 4 + 1] = sA; dbuf[n * 4 + 3] = sB; }

    // epilogue: apply We^T to S once per node
    float E0 = 0.f, E1 = 0.f;
    #pragma unroll
    for (int d = 0; d < 32; d++){
        float s0 = __shfl(S0, hsel + d);
        float s1 = __shfl(S1, hsel + d);
        E0 = fmaf(WeR[d * HC + c0], s0, E0);
        E1 = fmaf(WeR[d * HC + c1], s1, E1);
    }

    float o0 = (acc0 + E0) / (sA + 1e-16f) + skip[(size_t)n * HC + c0];
    float o1 = (acc1 + E1) / (sB + 1e-16f) + skip[(size_t)n * HC + c1];

    if (apply_ln){
        float s1 = o0 + o1, s2 = o0 * o0 + o1 * o1;
        #pragma unroll
        for (int off = 32; off; off >>= 1){
            s1 += __shfl_xor(s1, off);
            s2 += __shfl_xor(s2, off);
        }
        float m = s1 * (1.f / 128.f);
        float var = s2 * (1.f / 128.f) - m * m;
        float inv = rsqrtf(var + 1e-5f);
        o0 = fmaxf((o0 - m) * inv * g[c0] + be[c0], 0.f);
        o1 = fmaxf((o1 - m) * inv * g[c1] + be[c1], 0.f);
    }
    out[(size_t)n * HC + c0] = o0;
    out[(size_t)n * HC + c1] = o1;
}

// ---- a = exp(raw - m[dst]) / (den[dst] + 1e-16) ----
__global__ void norm_a_kernel(float* __restrict__ a, const float* __restrict__ mbuf,
                              const float* __restrict__ dbuf, const int* __restrict__ dst,
                              int n){   // n = E*4
    int i = blockIdx.x * blockDim.x + threadIdx.x;
    if (i < n){
        int e = i >> 2, h = i & 3;
        int d = dst[e];
        a[i] = __expf(a[i] - mbuf[d * 4 + h]) / (dbuf[d * 4 + h] + 1e-16f);
    }
}

// ============================ launch ============================

extern "C" void kernel_launch(void* const* d_in, const int* in_sizes, int n_in,
                              void* d_out, int out_size, void* d_ws, size_t ws_size,
                              hipStream_t stream) {
    const float* x    = (const float*)d_in[0];
    const int*   ei   = (const int*)  d_in[1];
    const float* attr = (const float*)d_in[2];
    const float* gln[2]  = { (const float*)d_in[30], (const float*)d_in[32] };
    const float* beln[2] = { (const float*)d_in[31], (const float*)d_in[33] };

    float* out   = (float*)d_out;
    float* h_out = out;                               // [N,128]
    float* a_out[3] = { out + (size_t)N_NODES * HC,
                        out + (size_t)N_NODES * HC + (size_t)E_EDGES * 4,
                        out + (size_t)N_NODES * HC + (size_t)2 * E_EDGES * 4 };

    float* ws = (float*)d_ws;
    const size_t NB = (size_t)N_NODES * HC;
    float* H    = ws;            // layer activations [N,128]
    float* qbuf = ws + NB;
    float* kbuf = ws + 2 * NB;
    float* vbuf = ws + 3 * NB;
    float* sbuf = ws + 4 * NB;   // skip = x@Ws + bs
    float* mbuf = ws + 5 * NB;                    // [N,4]
    float* dbuf = mbuf + (size_t)N_NODES * 4;     // [N,4]
    int* ibase  = (int*)(dbuf + (size_t)N_NODES * 4);
    int* rowptr = ibase;                    // [N+1]
    int* cnt    = rowptr + N_NODES + 1;     // [N]
    int* cursor = cnt + N_NODES;            // [N]
    // pad to 8-byte alignment for int2
    int2* es    = (int2*)(cursor + N_NODES + 1);   // [E] (edge id, src)

    const int* srcp = ei;
    const int* dstp = ei + E_EDGES;

    // ---- CSR build (once per launch, reused for all 3 layers) ----
    zero_int_kernel<<<(N_NODES + 255) / 256, 256, 0, stream>>>(cnt, N_NODES);
    hist_kernel<<<(E_EDGES + 255) / 256, 256, 0, stream>>>(dstp, cnt, E_EDGES);
    scan_kernel<<<1, 1024, 0, stream>>>(cnt, rowptr, cursor);
    scatter_kernel<<<(E_EDGES + 255) / 256, 256, 0, stream>>>(srcp, dstp, cursor, es, E_EDGES);

    for (int l = 0; l < 3; l++){
        const float* Wq = (const float*)d_in[3 + 9 * l + 0];
        const float* bq = (const float*)d_in[3 + 9 * l + 1];
        const float* Wk = (const float*)d_in[3 + 9 * l + 2];
        const float* bk = (const float*)d_in[3 + 9 * l + 3];
        const float* Wv = (const float*)d_in[3 + 9 * l + 4];
        const float* bv = (const float*)d_in[3 + 9 * l + 5];
        const float* We = (const float*)d_in[3 + 9 * l + 6];
        const float* Ws = (const float*)d_in[3 + 9 * l + 7];
        const float* bs = (const float*)d_in[3 + 9 * l + 8];
        const float* Xin = (l == 0) ? x : H;

        const int gemm_grid = (N_NODES + 15) / 16;
        if (l == 0){
            gemm_node<256><<<gemm_grid, 128, 0, stream>>>(Xin, Wq, bq, qbuf, N_NODES);
            gemm_node<256><<<gemm_grid, 128, 0, stream>>>(Xin, Wk, bk, kbuf, N_NODES);
            gemm_node<256><<<gemm_grid, 128, 0, stream>>>(Xin, Wv, bv, vbuf, N_NODES);
            gemm_node<256><<<gemm_grid, 128, 0, stream>>>(Xin, Ws, bs, sbuf, N_NODES);
        } else {
            gemm_node<128><<<gemm_grid, 128, 0, stream>>>(Xin, Wq, bq, qbuf, N_NODES);
            gemm_node<128><<<gemm_grid, 128, 0, stream>>>(Xin, Wk, bk, kbuf, N_NODES);
            gemm_node<128><<<gemm_grid, 128, 0, stream>>>(Xin, Wv, bv, vbuf, N_NODES);
            gemm_node<128><<<gemm_grid, 128, 0, stream>>>(Xin, Ws, bs, sbuf, N_NODES);
        }

        float* dest = (l < 2) ? H : h_out;
        const float* gg = (l < 2) ? gln[l] : nullptr;
        const float* bb = (l < 2) ? beln[l] : nullptr;
        fused_attn_kernel<<<(N_NODES + 3) / 4, 256, 0, stream>>>(
            qbuf, kbuf, vbuf, sbuf, attr, We, rowptr, es,
            a_out[l], mbuf, dbuf, gg, bb, dest, (l < 2) ? 1 : 0);

        norm_a_kernel<<<(E_EDGES * 4 + 255) / 256, 256, 0, stream>>>(
            a_out[l], mbuf, dbuf, dstp, E_EDGES * 4);
    }
}

// Round 4
// 2067.311 us; speedup vs baseline: 2.0558x; 1.2062x over previous
//
#include <hip/hip_runtime.h>
#include <math.h>

#define N_NODES 50000
#define E_EDGES 800000
#define HC 128
#define ED 32
#define WTS 33   // padded LDS stride for transposed We (bank-conflict-free)

// ============================ CSR build ============================

__global__ void zero_int_kernel(int* __restrict__ p, int n){
    int i = blockIdx.x * blockDim.x + threadIdx.x;
    if (i < n) p[i] = 0;
}

__global__ void hist_kernel(const int* __restrict__ dst, int* __restrict__ cnt, int n_edges){
    int e = blockIdx.x * blockDim.x + threadIdx.x;
    if (e < n_edges) atomicAdd(&cnt[dst[e]], 1);
}

// single block of 1024 threads: exclusive scan of cnt[N] -> rowptr[N+1] and cursor[N]
__global__ void scan_kernel(const int* __restrict__ cnt, int* __restrict__ rowptr,
                            int* __restrict__ cursor){
    __shared__ int part[1024];
    const int t = threadIdx.x;
    const int CH = (N_NODES + 1023) / 1024;   // 49
    const int base = t * CH;
    int s = 0;
    for (int i = 0; i < CH; i++){
        int idx = base + i;
        if (idx < N_NODES) s += cnt[idx];
    }
    part[t] = s;
    __syncthreads();
    for (int off = 1; off < 1024; off <<= 1){
        int v = (t >= off) ? part[t - off] : 0;
        __syncthreads();
        part[t] += v;
        __syncthreads();
    }
    int off = (t == 0) ? 0 : part[t - 1];
    for (int i = 0; i < CH; i++){
        int idx = base + i;
        if (idx < N_NODES){
            int c = cnt[idx];
            rowptr[idx] = off;
            cursor[idx] = off;
            off += c;
        }
    }
    if (t == 1023) rowptr[N_NODES] = part[1023];
}

__global__ void scatter_kernel(const int* __restrict__ src, const int* __restrict__ dst,
                               int* __restrict__ cursor, int2* __restrict__ es, int n_edges){
    int e = blockIdx.x * blockDim.x + threadIdx.x;
    if (e < n_edges){
        int d = dst[e];
        int pos = atomicAdd(&cursor[d], 1);
        es[pos] = make_int2(e, src[e]);
    }
}

// permute attr rows into CSR order: one 32-lane group per row (coalesced write)
__global__ void permute_attr_kernel(const float* __restrict__ attr, const int2* __restrict__ es,
                                    float* __restrict__ attr_csr, int n_edges){
    int gid = blockIdx.x * blockDim.x + threadIdx.x;
    int grp = gid >> 5, lane = gid & 31;
    if (grp < n_edges){
        int e = es[grp].x;
        attr_csr[(size_t)grp * ED + lane] = attr[(size_t)e * ED + lane];
    }
}

// ============================ node GEMM x4 ============================
// Yi[n_rows,128] = X[n_rows,K] @ Wi[K,128] + bi  for i in {q,k,v,s};
// X tile staged in LDS once, reused for all four weight matrices.
template<int K>
__global__ __launch_bounds__(128) void gemm_node4(
    const float* __restrict__ X,
    const float* __restrict__ Wq, const float* __restrict__ bq, float* __restrict__ Yq,
    const float* __restrict__ Wk, const float* __restrict__ bk, float* __restrict__ Yk,
    const float* __restrict__ Wv, const float* __restrict__ bv, float* __restrict__ Yv,
    const float* __restrict__ Ws, const float* __restrict__ bs, float* __restrict__ Ys,
    int n_rows)
{
    __shared__ __align__(16) float xs[16 * K];
    const int t = threadIdx.x;            // 0..127 = output column
    const int row0 = blockIdx.x * 16;
    for (int idx = t; idx < 16 * K; idx += 128){
        int r = idx / K, c = idx % K;
        int row = row0 + r;
        xs[idx] = (row < n_rows) ? X[row * K + c] : 0.f;
    }
    __syncthreads();

    const float* Wp[4] = {Wq, Wk, Wv, Ws};
    const float* bp[4] = {bq, bk, bv, bs};
    float*       Yp[4] = {Yq, Yk, Yv, Ys};

    for (int w = 0; w < 4; w++){
        const float* W = Wp[w];
        float acc[16];
        const float bias = bp[w][t];
        #pragma unroll
        for (int r = 0; r < 16; r++) acc[r] = bias;
        for (int kk = 0; kk < K; kk += 4){
            float w0 = W[(kk + 0) * HC + t];
            float w1 = W[(kk + 1) * HC + t];
            float w2 = W[(kk + 2) * HC + t];
            float w3 = W[(kk + 3) * HC + t];
            #pragma unroll
            for (int r = 0; r < 16; r++){
                float4 xv = *(const float4*)&xs[r * K + kk];
                acc[r] += xv.x * w0 + xv.y * w1 + xv.z * w2 + xv.w * w3;
            }
        }
        float* Y = Yp[w];
        #pragma unroll
        for (int r = 0; r < 16; r++){
            int row = row0 + r;
            if (row < n_rows) Y[row * HC + t] = acc[r];
        }
    }
}

// ===================== fused per-node attention =====================
// One wave per destination node; online softmax in registers; algebraic
// refactor keeps the per-edge body free of any 32-iter mat-vec:
//   alpha = (q.k[src] + attr . QW[dst]) / sqrt(32)
//   edge-proj part of output = We^T S,  S[h,d] = sum_e w_e[h] attr[e,d]
__global__ __launch_bounds__(256) void fused_attn_kernel(
    const float* __restrict__ q, const float* __restrict__ k, const float* __restrict__ v,
    const float* __restrict__ skip, const float* __restrict__ attr,
    const float* __restrict__ attr_csr, int perm_mode,
    const float* __restrict__ We,
    const int* __restrict__ rowptr, const int2* __restrict__ es,
    float* __restrict__ a_raw, float* __restrict__ mbuf, float* __restrict__ dbuf,
    const float* __restrict__ g, const float* __restrict__ be,
    float* __restrict__ out, int apply_ln)
{
    // single transposed+padded We: WeT[c*33 + d] = We[d*128 + c]
    // staging: coalesced global read, LDS write bank = (c+d)&31 -> conflict-free
    __shared__ float WeT[HC * WTS];
    const int t = threadIdx.x;
    for (int idx = t; idx < ED * HC; idx += 256){
        float w = We[idx];
        int d = idx >> 7, c = idx & 127;
        WeT[c * WTS + d] = w;
    }
    __syncthreads();

    const int lane = t & 63, wv = t >> 6;
    const int n = blockIdx.x * 4 + wv;
    if (n >= N_NODES) return;
    const int c0 = lane, c1 = lane + 64;
    const int hsel = lane & 32;      // head-group base channel within the wave
    const int d0 = lane & 31;

    const float q0 = q[(size_t)n * HC + c0];
    const float q1 = q[(size_t)n * HC + c1];
    const float sk0 = skip[(size_t)n * HC + c0];   // issue early, used in epilogue
    const float sk1 = skip[(size_t)n * HC + c1];

    // QW for this lane's two (h,d) slots — once per node
    float QW0 = 0.f, QW1 = 0.f;
    #pragma unroll
    for (int c = 0; c < 32; c++){
        float sq0 = __shfl(q0, hsel + c);
        float sq1 = __shfl(q1, hsel + c);
        QW0 = fmaf(sq0, WeT[(hsel + c) * WTS + d0], QW0);
        QW1 = fmaf(sq1, WeT[(64 + hsel + c) * WTS + d0], QW1);
    }

    const int beg = rowptr[n], end = rowptr[n + 1];
    float mA = -1e30f, sA = 0.f, acc0 = 0.f, S0 = 0.f;  // heads (lane<32 ? 0 : 1)
    float mB = -1e30f, sB = 0.f, acc1 = 0.f, S1 = 0.f;  // heads (lane<32 ? 2 : 3)

    auto process = [&](int e, float av, float k0, float k1, float v0, float v1){
        float p0 = fmaf(av, QW0, q0 * k0);
        float p1 = fmaf(av, QW1, q1 * k1);
        #pragma unroll
        for (int off = 16; off; off >>= 1){
            p0 += __shfl_xor(p0, off);
            p1 += __shfl_xor(p1, off);
        }
        const float aA = p0 * 0.17677669529663687f;  // 1/sqrt(32)
        const float aB = p1 * 0.17677669529663687f;
        if (lane == 0)       { a_raw[(size_t)e * 4 + 0] = aA; a_raw[(size_t)e * 4 + 2] = aB; }
        else if (lane == 32) { a_raw[(size_t)e * 4 + 1] = aA; a_raw[(size_t)e * 4 + 3] = aB; }
        float mAn = fmaxf(mA, aA);
        float scA = __expf(mA - mAn), wA = __expf(aA - mAn);
        sA = fmaf(sA, scA, wA);
        acc0 = fmaf(acc0, scA, wA * v0);
        S0   = fmaf(S0,   scA, wA * av);
        mA = mAn;
        float mBn = fmaxf(mB, aB);
        float scB = __expf(mB - mBn), wB = __expf(aB - mBn);
        sB = fmaf(sB, scB, wB);
        acc1 = fmaf(acc1, scB, wB * v1);
        S1   = fmaf(S1,   scB, wB * av);
        mB = mBn;
    };

    int i = beg;
    for (; i + 1 < end; i += 2){
        int2 ea = es[i], eb = es[i + 1];
        float av0, av1;
        if (perm_mode){
            // CSR-ordered attr: sequential, independent of es -> issues immediately
            av0 = attr_csr[(size_t)i * ED + d0];
            av1 = attr_csr[(size_t)(i + 1) * ED + d0];
        } else {
            av0 = attr[(size_t)ea.x * ED + d0];
            av1 = attr[(size_t)eb.x * ED + d0];
        }
        const float* kp0 = k + (size_t)ea.y * HC;
        const float* vp0 = v + (size_t)ea.y * HC;
        const float* kp1 = k + (size_t)eb.y * HC;
        const float* vp1 = v + (size_t)eb.y * HC;
        float k00 = kp0[c0], k01 = kp0[c1], v00 = vp0[c0], v01 = vp0[c1];
        float k10 = kp1[c0], k11 = kp1[c1], v10 = vp1[c0], v11 = vp1[c1];
        process(ea.x, av0, k00, k01, v00, v01);
        process(eb.x, av1, k10, k11, v10, v11);
    }
    if (i < end){
        int2 ea = es[i];
        float av0 = perm_mode ? attr_csr[(size_t)i * ED + d0]
                              : attr[(size_t)ea.x * ED + d0];
        const float* kp0 = k + (size_t)ea.y * HC;
        const float* vp0 = v + (size_t)ea.y * HC;
        process(ea.x, av0, kp0[c0], kp0[c1], vp0[c0], vp0[c1]);
    }

    if (lane == 0)       { mbuf[n * 4 + 0] = mA; mbuf[n * 4 + 2] = mB;
                           dbuf[n * 4 + 0] = sA; dbuf[n * 4 + 2] = sB; }
    else if (lane == 32) { mbuf[n * 4 + 1] = mA; mbuf[n * 4 + 3] = mB;
                           dbuf[n * 4 + 1] = sA; dbuf[n * 4 + 3] = sB; }

    // epilogue: apply We^T to S once per node (WeT read: bank (lane+d)&31, conflict-free)
    float E0 = 0.f, E1 = 0.f;
    #pragma unroll
    for (int d = 0; d < 32; d++){
        float s0 = __shfl(S0, hsel + d);
        float s1 = __shfl(S1, hsel + d);
        E0 = fmaf(WeT[c0 * WTS + d], s0, E0);
        E1 = fmaf(WeT[c1 * WTS + d], s1, E1);
    }

    float o0 = (acc0 + E0) / (sA + 1e-16f) + sk0;
    float o1 = (acc1 + E1) / (sB + 1e-16f) + sk1;

    if (apply_ln){
        float s1 = o0 + o1, s2 = o0 * o0 + o1 * o1;
        #pragma unroll
        for (int off = 32; off; off >>= 1){
            s1 += __shfl_xor(s1, off);
            s2 += __shfl_xor(s2, off);
        }
        float m = s1 * (1.f / 128.f);
        float var = s2 * (1.f / 128.f) - m * m;
        float inv = rsqrtf(var + 1e-5f);
        o0 = fmaxf((o0 - m) * inv * g[c0] + be[c0], 0.f);
        o1 = fmaxf((o1 - m) * inv * g[c1] + be[c1], 0.f);
    }
    out[(size_t)n * HC + c0] = o0;
    out[(size_t)n * HC + c1] = o1;
}

// ---- a = exp(raw - m[dst]) / (den[dst] + 1e-16) ----
__global__ void norm_a_kernel(float* __restrict__ a, const float* __restrict__ mbuf,
                              const float* __restrict__ dbuf, const int* __restrict__ dst,
                              int n){   // n = E*4
    int i = blockIdx.x * blockDim.x + threadIdx.x;
    if (i < n){
        int e = i >> 2, h = i & 3;
        int d = dst[e];
        a[i] = __expf(a[i] - mbuf[d * 4 + h]) / (dbuf[d * 4 + h] + 1e-16f);
    }
}

// ============================ launch ============================

extern "C" void kernel_launch(void* const* d_in, const int* in_sizes, int n_in,
                              void* d_out, int out_size, void* d_ws, size_t ws_size,
                              hipStream_t stream) {
    const float* x    = (const float*)d_in[0];
    const int*   ei   = (const int*)  d_in[1];
    const float* attr = (const float*)d_in[2];
    const float* gln[2]  = { (const float*)d_in[30], (const float*)d_in[32] };
    const float* beln[2] = { (const float*)d_in[31], (const float*)d_in[33] };

    float* out   = (float*)d_out;
    float* h_out = out;                               // [N,128]
    float* a_out[3] = { out + (size_t)N_NODES * HC,
                        out + (size_t)N_NODES * HC + (size_t)E_EDGES * 4,
                        out + (size_t)N_NODES * HC + (size_t)2 * E_EDGES * 4 };

    float* ws = (float*)d_ws;
    const size_t NB = (size_t)N_NODES * HC;
    float* H    = ws;            // layer activations [N,128]
    float* qbuf = ws + NB;
    float* kbuf = ws + 2 * NB;
    float* vbuf = ws + 3 * NB;
    float* sbuf = ws + 4 * NB;   // skip = x@Ws + bs
    float* mbuf = ws + 5 * NB;                    // [N,4]
    float* dbuf = mbuf + (size_t)N_NODES * 4;     // [N,4]
    int* ibase  = (int*)(dbuf + (size_t)N_NODES * 4);
    int* rowptr = ibase;                    // [N+1]
    int* cnt    = rowptr + N_NODES + 1;     // [N]
    int* cursor = cnt + N_NODES;            // [N]
    int2* es    = (int2*)(cursor + N_NODES + 1);   // [E] (edge id, src); 8B-aligned
    float* attr_csr = (float*)(es + E_EDGES);      // [E*32] (optional)

    const size_t need_bytes = (size_t)((char*)(attr_csr + (size_t)E_EDGES * ED) - (char*)d_ws);
    const int perm_mode = (ws_size >= need_bytes) ? 1 : 0;

    const int* srcp = ei;
    const int* dstp = ei + E_EDGES;

    // ---- CSR build (once per launch, reused for all 3 layers) ----
    zero_int_kernel<<<(N_NODES + 255) / 256, 256, 0, stream>>>(cnt, N_NODES);
    hist_kernel<<<(E_EDGES + 255) / 256, 256, 0, stream>>>(dstp, cnt, E_EDGES);
    scan_kernel<<<1, 1024, 0, stream>>>(cnt, rowptr, cursor);
    scatter_kernel<<<(E_EDGES + 255) / 256, 256, 0, stream>>>(srcp, dstp, cursor, es, E_EDGES);
    if (perm_mode)
        permute_attr_kernel<<<(E_EDGES * 32 + 255) / 256, 256, 0, stream>>>(attr, es, attr_csr, E_EDGES);

    for (int l = 0; l < 3; l++){
        const float* Wq = (const float*)d_in[3 + 9 * l + 0];
        const float* bq = (const float*)d_in[3 + 9 * l + 1];
        const float* Wk = (const float*)d_in[3 + 9 * l + 2];
        const float* bk = (const float*)d_in[3 + 9 * l + 3];
        const float* Wv = (const float*)d_in[3 + 9 * l + 4];
        const float* bv = (const float*)d_in[3 + 9 * l + 5];
        const float* We = (const float*)d_in[3 + 9 * l + 6];
        const float* Ws = (const float*)d_in[3 + 9 * l + 7];
        const float* bs = (const float*)d_in[3 + 9 * l + 8];
        const float* Xin = (l == 0) ? x : H;

        const int gemm_grid = (N_NODES + 15) / 16;
        if (l == 0){
            gemm_node4<256><<<gemm_grid, 128, 0, stream>>>(Xin, Wq, bq, qbuf, Wk, bk, kbuf,
                                                           Wv, bv, vbuf, Ws, bs, sbuf, N_NODES);
        } else {
            gemm_node4<128><<<gemm_grid, 128, 0, stream>>>(Xin, Wq, bq, qbuf, Wk, bk, kbuf,
                                                           Wv, bv, vbuf, Ws, bs, sbuf, N_NODES);
        }

        float* dest = (l < 2) ? H : h_out;
        const float* gg = (l < 2) ? gln[l] : nullptr;
        const float* bb = (l < 2) ? beln[l] : nullptr;
        fused_attn_kernel<<<(N_NODES + 3) / 4, 256, 0, stream>>>(
            qbuf, kbuf, vbuf, sbuf, attr, attr_csr, perm_mode, We, rowptr, es,
            a_out[l], mbuf, dbuf, gg, bb, dest, (l < 2) ? 1 : 0);

        norm_a_kernel<<<(E_EDGES * 4 + 255) / 256, 256, 0, stream>>>(
            a_out[l], mbuf, dbuf, dstp, E_EDGES * 4);
    }
}

// Round 5
// 1438.920 us; speedup vs baseline: 2.9536x; 1.4367x over previous
//
#include <hip/hip_runtime.h>
#include <math.h>

#define N_NODES 50000
#define E_EDGES 800000
#define HC 128
#define ED 32
#define WTS 33   // padded LDS stride for transposed We (bank-conflict-free)

typedef __attribute__((ext_vector_type(8))) short bf16x8;
typedef __attribute__((ext_vector_type(4))) float f32x4;
typedef unsigned short ushort_t;

__device__ __forceinline__ ushort_t f2bf(float f){
    unsigned u = __float_as_uint(f);
    return (ushort_t)((u + 0x7FFFu + ((u >> 16) & 1u)) >> 16);   // RNE
}

// ============================ CSR build ============================

__global__ void zero_int_kernel(int* __restrict__ p, int n){
    int i = blockIdx.x * blockDim.x + threadIdx.x;
    if (i < n) p[i] = 0;
}

__global__ void hist_kernel(const int* __restrict__ dst, int* __restrict__ cnt, int n_edges){
    int e = blockIdx.x * blockDim.x + threadIdx.x;
    if (e < n_edges) atomicAdd(&cnt[dst[e]], 1);
}

__global__ void scan_kernel(const int* __restrict__ cnt, int* __restrict__ rowptr,
                            int* __restrict__ cursor){
    __shared__ int part[1024];
    const int t = threadIdx.x;
    const int CH = (N_NODES + 1023) / 1024;
    const int base = t * CH;
    int s = 0;
    for (int i = 0; i < CH; i++){
        int idx = base + i;
        if (idx < N_NODES) s += cnt[idx];
    }
    part[t] = s;
    __syncthreads();
    for (int off = 1; off < 1024; off <<= 1){
        int v = (t >= off) ? part[t - off] : 0;
        __syncthreads();
        part[t] += v;
        __syncthreads();
    }
    int off = (t == 0) ? 0 : part[t - 1];
    for (int i = 0; i < CH; i++){
        int idx = base + i;
        if (idx < N_NODES){
            int c = cnt[idx];
            rowptr[idx] = off;
            cursor[idx] = off;
            off += c;
        }
    }
    if (t == 1023) rowptr[N_NODES] = part[1023];
}

__global__ void scatter_kernel(const int* __restrict__ src, const int* __restrict__ dst,
                               int* __restrict__ cursor, int2* __restrict__ es, int n_edges){
    int e = blockIdx.x * blockDim.x + threadIdx.x;
    if (e < n_edges){
        int d = dst[e];
        int pos = atomicAdd(&cursor[d], 1);
        es[pos] = make_int2(e, src[e]);
    }
}

__global__ void permute_attr_kernel(const float* __restrict__ attr, const int2* __restrict__ es,
                                    float* __restrict__ attr_csr, int n_edges){
    int gid = blockIdx.x * blockDim.x + threadIdx.x;
    int grp = gid >> 5, lane = gid & 31;
    if (grp < n_edges){
        int e = es[grp].x;
        attr_csr[(size_t)grp * ED + lane] = attr[(size_t)e * ED + lane];
    }
}

// ===================== bf16 conversion / weight packing =====================

// fp32 -> bf16, 4 elements per thread
__global__ void convert_bf16_kernel(const float* __restrict__ X, ushort_t* __restrict__ Y,
                                    int n4){   // n4 = n_elements/4
    int i = blockIdx.x * blockDim.x + threadIdx.x;
    if (i < n4){
        float4 v = ((const float4*)X)[i];
        ushort_t r0 = f2bf(v.x), r1 = f2bf(v.y), r2 = f2bf(v.z), r3 = f2bf(v.w);
        ((ushort4*)Y)[i] = make_ushort4(r0, r1, r2, r3);
    }
}

// pack Wq|Wk|Wv|Ws [K,128] fp32 into fragment-ordered bf16:
// Bpack[((k>>3)*512 + n)*8 + (k&7)] = W_{n>>7}[k*128 + (n&127)]
__global__ void pack_w_kernel(const float* __restrict__ Wq, const float* __restrict__ Wk,
                              const float* __restrict__ Wv, const float* __restrict__ Ws,
                              ushort_t* __restrict__ Bpack, int K){
    int t = blockIdx.x * blockDim.x + threadIdx.x;
    if (t >= K * 512) return;
    int n = t & 511, k = t >> 9;
    const float* W = (n < 128) ? Wq : (n < 256) ? Wk : (n < 384) ? Wv : Ws;
    float val = W[k * HC + (n & 127)];
    Bpack[(((size_t)(k >> 3)) * 512 + n) * 8 + (k & 7)] = f2bf(val);
}

// ===================== MFMA GEMM: [M,K]bf16 @ [K,512]bf16 + bias -> 4x [M,128]f32 ====
// block = 4 waves; wave w computes output matrix w (cols w*128..w*128+127).
// BM=32: per wave 2 m-tiles x 8 n-tiles of mfma_f32_16x16x32_bf16.
// A frag:  A[m=lane&15][k=(lane>>4)*8+j]  -> 16B contiguous in row-major bf16
// B frag:  B[k=(lane>>4)*8+j][n=lane&15]  -> 16B contiguous in Bpack order
// C/D:     D[row=(lane>>4)*4+r][col=lane&15]
template<int K>
__global__ __launch_bounds__(256) void gemm_mfma(
    const ushort_t* __restrict__ Xbf, const ushort_t* __restrict__ Bpack,
    const float* __restrict__ bq, const float* __restrict__ bk,
    const float* __restrict__ bv, const float* __restrict__ bs,
    float* __restrict__ Yq, float* __restrict__ Yk,
    float* __restrict__ Yv, float* __restrict__ Ys, int M)
{
    const int w = threadIdx.x >> 6;
    const int lane = threadIdx.x & 63;
    const int q = lane >> 4, nn = lane & 15;
    const int row0 = blockIdx.x * 32;

    f32x4 acc[2][8];
    #pragma unroll
    for (int mt = 0; mt < 2; mt++)
        #pragma unroll
        for (int nt = 0; nt < 8; nt++)
            acc[mt][nt] = (f32x4){0.f, 0.f, 0.f, 0.f};

    const int r0 = row0 + nn;            // m-tile 0 row for A frags
    const int r1 = row0 + 16 + nn;       // m-tile 1 row
    const bf16x8 zf = (bf16x8){0,0,0,0,0,0,0,0};

    #pragma unroll
    for (int kc = 0; kc < K / 32; kc++){
        bf16x8 a0 = (r0 < M) ? *(const bf16x8*)&Xbf[(size_t)r0 * K + kc * 32 + q * 8] : zf;
        bf16x8 a1 = (r1 < M) ? *(const bf16x8*)&Xbf[(size_t)r1 * K + kc * 32 + q * 8] : zf;
        bf16x8 b[8];
        #pragma unroll
        for (int nt = 0; nt < 8; nt++){
            int n = w * 128 + nt * 16 + nn;
            b[nt] = *(const bf16x8*)&Bpack[(((size_t)(kc * 4 + q)) * 512 + n) * 8];
        }
        #pragma unroll
        for (int nt = 0; nt < 8; nt++){
            acc[0][nt] = __builtin_amdgcn_mfma_f32_16x16x32_bf16(a0, b[nt], acc[0][nt], 0, 0, 0);
            acc[1][nt] = __builtin_amdgcn_mfma_f32_16x16x32_bf16(a1, b[nt], acc[1][nt], 0, 0, 0);
        }
    }

    const float* bias_p[4] = {bq, bk, bv, bs};
    float*       Yp[4]     = {Yq, Yk, Yv, Ys};
    float* Y = Yp[w];
    const float* bias = bias_p[w];
    #pragma unroll
    for (int nt = 0; nt < 8; nt++){
        int col = nt * 16 + nn;
        float bval = bias[col];
        #pragma unroll
        for (int mt = 0; mt < 2; mt++){
            #pragma unroll
            for (int r = 0; r < 4; r++){
                int row = row0 + mt * 16 + q * 4 + r;
                if (row < M) Y[(size_t)row * HC + col] = acc[mt][nt][r] + bval;
            }
        }
    }
}

// ===================== fused per-node attention =====================
__global__ __launch_bounds__(256) void fused_attn_kernel(
    const float* __restrict__ q, const float* __restrict__ k, const float* __restrict__ v,
    const float* __restrict__ skip, const float* __restrict__ attr,
    const float* __restrict__ attr_csr, int perm_mode,
    const float* __restrict__ We,
    const int* __restrict__ rowptr, const int2* __restrict__ es,
    float* __restrict__ a_raw, float* __restrict__ mbuf, float* __restrict__ dbuf,
    const float* __restrict__ g, const float* __restrict__ be,
    float* __restrict__ out_f32, ushort_t* __restrict__ out_bf, int apply_ln)
{
    __shared__ float WeT[HC * WTS];   // WeT[c*33+d] = We[d*128+c]; conflict-free both ways
    const int t = threadIdx.x;
    for (int idx = t; idx < ED * HC; idx += 256){
        float wv_ = We[idx];
        int d = idx >> 7, c = idx & 127;
        WeT[c * WTS + d] = wv_;
    }
    __syncthreads();

    const int lane = t & 63, wv = t >> 6;
    const int n = blockIdx.x * 4 + wv;
    if (n >= N_NODES) return;
    const int c0 = lane, c1 = lane + 64;
    const int hsel = lane & 32;
    const int d0 = lane & 31;

    const float q0 = q[(size_t)n * HC + c0];
    const float q1 = q[(size_t)n * HC + c1];
    const float sk0 = skip[(size_t)n * HC + c0];
    const float sk1 = skip[(size_t)n * HC + c1];

    float QW0 = 0.f, QW1 = 0.f;
    #pragma unroll
    for (int c = 0; c < 32; c++){
        float sq0 = __shfl(q0, hsel + c);
        float sq1 = __shfl(q1, hsel + c);
        QW0 = fmaf(sq0, WeT[(hsel + c) * WTS + d0], QW0);
        QW1 = fmaf(sq1, WeT[(64 + hsel + c) * WTS + d0], QW1);
    }

    const int beg = rowptr[n], end = rowptr[n + 1];
    float mA = -1e30f, sA = 0.f, acc0 = 0.f, S0 = 0.f;
    float mB = -1e30f, sB = 0.f, acc1 = 0.f, S1 = 0.f;

    auto process = [&](int e, float av, float k0, float k1, float v0, float v1){
        float p0 = fmaf(av, QW0, q0 * k0);
        float p1 = fmaf(av, QW1, q1 * k1);
        #pragma unroll
        for (int off = 16; off; off >>= 1){
            p0 += __shfl_xor(p0, off);
            p1 += __shfl_xor(p1, off);
        }
        const float aA = p0 * 0.17677669529663687f;
        const float aB = p1 * 0.17677669529663687f;
        if (lane == 0)       { a_raw[(size_t)e * 4 + 0] = aA; a_raw[(size_t)e * 4 + 2] = aB; }
        else if (lane == 32) { a_raw[(size_t)e * 4 + 1] = aA; a_raw[(size_t)e * 4 + 3] = aB; }
        float mAn = fmaxf(mA, aA);
        float scA = __expf(mA - mAn), wA = __expf(aA - mAn);
        sA = fmaf(sA, scA, wA);
        acc0 = fmaf(acc0, scA, wA * v0);
        S0   = fmaf(S0,   scA, wA * av);
        mA = mAn;
        float mBn = fmaxf(mB, aB);
        float scB = __expf(mB - mBn), wB = __expf(aB - mBn);
        sB = fmaf(sB, scB, wB);
        acc1 = fmaf(acc1, scB, wB * v1);
        S1   = fmaf(S1,   scB, wB * av);
        mB = mBn;
    };

    int i = beg;
    for (; i + 1 < end; i += 2){
        int2 ea = es[i], eb = es[i + 1];
        float av0, av1;
        if (perm_mode){
            av0 = attr_csr[(size_t)i * ED + d0];
            av1 = attr_csr[(size_t)(i + 1) * ED + d0];
        } else {
            av0 = attr[(size_t)ea.x * ED + d0];
            av1 = attr[(size_t)eb.x * ED + d0];
        }
        const float* kp0 = k + (size_t)ea.y * HC;
        const float* vp0 = v + (size_t)ea.y * HC;
        const float* kp1 = k + (size_t)eb.y * HC;
        const float* vp1 = v + (size_t)eb.y * HC;
        float k00 = kp0[c0], k01 = kp0[c1], v00 = vp0[c0], v01 = vp0[c1];
        float k10 = kp1[c0], k11 = kp1[c1], v10 = vp1[c0], v11 = vp1[c1];
        process(ea.x, av0, k00, k01, v00, v01);
        process(eb.x, av1, k10, k11, v10, v11);
    }
    if (i < end){
        int2 ea = es[i];
        float av0 = perm_mode ? attr_csr[(size_t)i * ED + d0]
                              : attr[(size_t)ea.x * ED + d0];
        const float* kp0 = k + (size_t)ea.y * HC;
        const float* vp0 = v + (size_t)ea.y * HC;
        process(ea.x, av0, kp0[c0], kp0[c1], vp0[c0], vp0[c1]);
    }

    if (lane == 0)       { mbuf[n * 4 + 0] = mA; mbuf[n * 4 + 2] = mB;
                           dbuf[n * 4 + 0] = sA; dbuf[n * 4 + 2] = sB; }
    else if (lane == 32) { mbuf[n * 4 + 1] = mA; mbuf[n * 4 + 3] = mB;
                           dbuf[n * 4 + 1] = sA; dbuf[n * 4 + 3] = sB; }

    float E0 = 0.f, E1 = 0.f;
    #pragma unroll
    for (int d = 0; d < 32; d++){
        float s0 = __shfl(S0, hsel + d);
        float s1 = __shfl(S1, hsel + d);
        E0 = fmaf(WeT[c0 * WTS + d], s0, E0);
        E1 = fmaf(WeT[c1 * WTS + d], s1, E1);
    }

    float o0 = (acc0 + E0) / (sA + 1e-16f) + sk0;
    float o1 = (acc1 + E1) / (sB + 1e-16f) + sk1;

    if (apply_ln){
        float s1 = o0 + o1, s2 = o0 * o0 + o1 * o1;
        #pragma unroll
        for (int off = 32; off; off >>= 1){
            s1 += __shfl_xor(s1, off);
            s2 += __shfl_xor(s2, off);
        }
        float m = s1 * (1.f / 128.f);
        float var = s2 * (1.f / 128.f) - m * m;
        float inv = rsqrtf(var + 1e-5f);
        o0 = fmaxf((o0 - m) * inv * g[c0] + be[c0], 0.f);
        o1 = fmaxf((o1 - m) * inv * g[c1] + be[c1], 0.f);
        // layers 0/1: H is consumed only by the next bf16 GEMM -> store bf16 directly
        out_bf[(size_t)n * HC + c0] = f2bf(o0);
        out_bf[(size_t)n * HC + c1] = f2bf(o1);
    } else {
        out_f32[(size_t)n * HC + c0] = o0;
        out_f32[(size_t)n * HC + c1] = o1;
    }
}

// ---- a = exp(raw - m[dst]) / (den[dst] + 1e-16) ----
__global__ void norm_a_kernel(float* __restrict__ a, const float* __restrict__ mbuf,
                              const float* __restrict__ dbuf, const int* __restrict__ dst,
                              int n){
    int i = blockIdx.x * blockDim.x + threadIdx.x;
    if (i < n){
        int e = i >> 2, h = i & 3;
        int d = dst[e];
        a[i] = __expf(a[i] - mbuf[d * 4 + h]) / (dbuf[d * 4 + h] + 1e-16f);
    }
}

// ============================ launch ============================

extern "C" void kernel_launch(void* const* d_in, const int* in_sizes, int n_in,
                              void* d_out, int out_size, void* d_ws, size_t ws_size,
                              hipStream_t stream) {
    const float* x    = (const float*)d_in[0];
    const int*   ei   = (const int*)  d_in[1];
    const float* attr = (const float*)d_in[2];
    const float* gln[2]  = { (const float*)d_in[30], (const float*)d_in[32] };
    const float* beln[2] = { (const float*)d_in[31], (const float*)d_in[33] };

    float* out   = (float*)d_out;
    float* h_out = out;
    float* a_out[3] = { out + (size_t)N_NODES * HC,
                        out + (size_t)N_NODES * HC + (size_t)E_EDGES * 4,
                        out + (size_t)N_NODES * HC + (size_t)2 * E_EDGES * 4 };

    // ---- workspace layout (64B-aligned chunks) ----
    char* base = (char*)d_ws;
    size_t off = 0;
    auto alloc = [&](size_t bytes) -> void* {
        void* p = base + off;
        off = (off + bytes + 63) & ~(size_t)63;
        return p;
    };
    const size_t NB = (size_t)N_NODES * HC;
    float* qbuf = (float*)alloc(NB * 4);
    float* kbuf = (float*)alloc(NB * 4);
    float* vbuf = (float*)alloc(NB * 4);
    float* sbuf = (float*)alloc(NB * 4);
    float* mbuf = (float*)alloc((size_t)N_NODES * 4 * 4);
    float* dbuf = (float*)alloc((size_t)N_NODES * 4 * 4);
    int* rowptr = (int*)alloc((N_NODES + 1) * 4);
    int* cnt    = (int*)alloc(N_NODES * 4);
    int* cursor = (int*)alloc(N_NODES * 4);
    int2* es    = (int2*)alloc((size_t)E_EDGES * 8);
    ushort_t* Xbf   = (ushort_t*)alloc((size_t)N_NODES * 256 * 2);
    ushort_t* Hbf   = (ushort_t*)alloc(NB * 2);
    ushort_t* Bpack = (ushort_t*)alloc((size_t)256 * 512 * 2);
    float* attr_csr = (float*)alloc((size_t)E_EDGES * ED * 4);
    const int perm_mode = (ws_size >= off) ? 1 : 0;

    const int* srcp = ei;
    const int* dstp = ei + E_EDGES;

    // ---- CSR build + conversions (once per launch) ----
    zero_int_kernel<<<(N_NODES + 255) / 256, 256, 0, stream>>>(cnt, N_NODES);
    hist_kernel<<<(E_EDGES + 255) / 256, 256, 0, stream>>>(dstp, cnt, E_EDGES);
    scan_kernel<<<1, 1024, 0, stream>>>(cnt, rowptr, cursor);
    scatter_kernel<<<(E_EDGES + 255) / 256, 256, 0, stream>>>(srcp, dstp, cursor, es, E_EDGES);
    if (perm_mode)
        permute_attr_kernel<<<(E_EDGES * 32 + 255) / 256, 256, 0, stream>>>(attr, es, attr_csr, E_EDGES);
    convert_bf16_kernel<<<((N_NODES * 256 / 4) + 255) / 256, 256, 0, stream>>>(x, Xbf, N_NODES * 256 / 4);

    const int gemm_grid = (N_NODES + 31) / 32;

    for (int l = 0; l < 3; l++){
        const float* Wq = (const float*)d_in[3 + 9 * l + 0];
        const float* bq = (const float*)d_in[3 + 9 * l + 1];
        const float* Wk = (const float*)d_in[3 + 9 * l + 2];
        const float* bk = (const float*)d_in[3 + 9 * l + 3];
        const float* Wv = (const float*)d_in[3 + 9 * l + 4];
        const float* bv = (const float*)d_in[3 + 9 * l + 5];
        const float* We = (const float*)d_in[3 + 9 * l + 6];
        const float* Ws = (const float*)d_in[3 + 9 * l + 7];
        const float* bs = (const float*)d_in[3 + 9 * l + 8];
        const int K = (l == 0) ? 256 : 128;

        pack_w_kernel<<<(K * 512 + 255) / 256, 256, 0, stream>>>(Wq, Wk, Wv, Ws, Bpack, K);
        if (l == 0)
            gemm_mfma<256><<<gemm_grid, 256, 0, stream>>>(Xbf, Bpack, bq, bk, bv, bs,
                                                          qbuf, kbuf, vbuf, sbuf, N_NODES);
        else
            gemm_mfma<128><<<gemm_grid, 256, 0, stream>>>(Hbf, Bpack, bq, bk, bv, bs,
                                                          qbuf, kbuf, vbuf, sbuf, N_NODES);

        const float* gg = (l < 2) ? gln[l] : nullptr;
        const float* bb = (l < 2) ? beln[l] : nullptr;
        fused_attn_kernel<<<(N_NODES + 3) / 4, 256, 0, stream>>>(
            qbuf, kbuf, vbuf, sbuf, attr, attr_csr, perm_mode, We, rowptr, es,
            a_out[l], mbuf, dbuf, gg, bb,
            (l < 2) ? nullptr : h_out, (l < 2) ? Hbf : nullptr, (l < 2) ? 1 : 0);

        norm_a_kernel<<<(E_EDGES * 4 + 255) / 256, 256, 0, stream>>>(
            a_out[l], mbuf, dbuf, dstp, E_EDGES * 4);
    }
}